// Round 3
// baseline (1608.551 us; speedup 1.0000x reference)
//
#include <hip/hip_runtime.h>
#include <hip/hip_bf16.h>

using bf16 = __hip_bfloat16;

#define DEV_INLINE __device__ __forceinline__

// Problem constants
constexpr int B_  = 4;
constexpr int LQ  = 3000;
constexpr int LK  = 750;
constexpr int NH_ = 4;
constexpr int TK  = 16;      // top-k
constexpr float EPSF = 1e-6f;

// Attention LDS layout constants
constexpr int PITCH_C = 752;  // bf16 K/V row pitch (cross kernel)
constexpr int PITCH_A = 751;  // fp32 K row pitch (awg kernel), odd => conflict-free staging
constexpr int TQ = 40;        // query rows per workgroup

// Workspace layout (fp32 elements). Total 4,992,000 floats = ~20 MB.
constexpr size_t WS_KV = 0;        // 6 x B*LK*64 = 1,152,000
constexpr size_t WS_XB = 1152000;  // B*LQ*64 = 768,000
constexpr size_t WS_QP = 1920000;  // 768,000
constexpr size_t WS_AO = 2688000;  // 768,000
constexpr size_t WS_QN = 3456000;  // 768,000
constexpr size_t WS_SG = 4224000;  // 768,000
constexpr size_t WS_HB = 1920000;  // aliases QP..SG (dead during FFN): B*LQ*256 = 3,072,000

DEV_INLINE float sigmoidf(float x) { return 1.f / (1.f + __expf(-x)); }

// LayerNorm across one wave (64 threads == one row of 64 features).
DEV_INLINE float row_ln(float v, float g, float b) {
  float s1 = v, s2 = v * v;
  #pragma unroll
  for (int off = 32; off > 0; off >>= 1) {
    s1 += __shfl_xor(s1, off);
    s2 += __shfl_xor(s2, off);
  }
  const float m   = s1 * (1.f / 64.f);
  const float var = s2 * (1.f / 64.f) - m * m;
  return (v - m) * rsqrtf(var + EPSF) * g + b;
}

// ---------------------------------------------------------------------------
// K/V projections for enc with all 6 weight matrices.
// grid (750, 6), block 256. Rows: 4 per block over B*LK=3000 rows.
// ---------------------------------------------------------------------------
__global__ __launch_bounds__(256) void kv_proj_kernel(
    const float* __restrict__ enc,
    const float* __restrict__ calWk, const float* __restrict__ calWv,
    const float* __restrict__ mWk, const float* __restrict__ mWv,
    float* __restrict__ kv)
{
  __shared__ float Wl[64 * 65];
  __shared__ float xs[4][64];
  const int t = threadIdx.x;
  const float* W;
  switch (blockIdx.y) {
    case 0: W = calWk; break;
    case 1: W = calWv; break;
    case 2: W = mWk; break;
    case 3: W = mWv; break;
    case 4: W = mWk + 4096; break;
    default: W = mWv + 4096; break;
  }
  for (int i = t; i < 4096; i += 256) Wl[(i >> 6) * 65 + (i & 63)] = W[i];
  const int rr = t >> 6, cc = t & 63;
  const size_t row = (size_t)blockIdx.x * 4 + rr;
  xs[rr][cc] = enc[row * 64 + cc];
  __syncthreads();
  float acc = 0.f;
  #pragma unroll
  for (int c = 0; c < 64; ++c) acc = fmaf(xs[rr][c], Wl[c * 65 + cc], acc);
  kv[(size_t)blockIdx.y * (3000 * 64) + row * 64 + cc] = acc;
}

// ---------------------------------------------------------------------------
// Generic 64x64 projection: out = (x @ W) * scale.  grid 3000, block 256.
// ---------------------------------------------------------------------------
__global__ __launch_bounds__(256) void proj_kernel(
    const float* __restrict__ x, const float* __restrict__ W,
    float* __restrict__ out, float scale)
{
  __shared__ float Wl[64 * 65];
  __shared__ float xs[4][64];
  const int t = threadIdx.x, rr = t >> 6, cc = t & 63;
  const size_t row = (size_t)blockIdx.x * 4 + rr;
  for (int i = t; i < 4096; i += 256) Wl[(i >> 6) * 65 + (i & 63)] = W[i];
  xs[rr][cc] = x[row * 64 + cc];
  __syncthreads();
  float acc = 0.f;
  #pragma unroll
  for (int c = 0; c < 64; ++c) acc = fmaf(xs[rr][c], Wl[c * 65 + cc], acc);
  out[row * 64 + cc] = acc * scale;
}

// ---------------------------------------------------------------------------
// Exact top-16 extraction over 750 logits held 12-per-lane (key = lane + 64*t).
// Iterative wave argmax with index tiebreak; winners broadcast to all lanes.
// ---------------------------------------------------------------------------
DEV_INLINE void extract16(const float (&lg)[12], const int lane,
                          float (&tv)[TK], int (&tk)[TK])
{
  float cur[12];
  #pragma unroll
  for (int t = 0; t < 12; ++t) cur[t] = lg[t];
  #pragma unroll
  for (int j = 0; j < TK; ++j) {
    float bv = cur[0];
    int   bk = lane;
    #pragma unroll
    for (int t = 1; t < 12; ++t) {
      const int k = lane + (t << 6);
      if (cur[t] > bv) { bv = cur[t]; bk = k; }
    }
    #pragma unroll
    for (int off = 32; off > 0; off >>= 1) {
      const float ov = __shfl_xor(bv, off);
      const int   ok = __shfl_xor(bk, off);
      if (ov > bv || (ov == bv && ok < bk)) { bv = ov; bk = ok; }
    }
    tv[j] = bv; tk[j] = bk;
    const int lt = bk - lane;   // == 64*t only for the owning lane
    #pragma unroll
    for (int t = 0; t < 12; ++t)
      if (lt == (t << 6)) cur[t] = -1e30f;
  }
}

// ---------------------------------------------------------------------------
// Fused attention. grid (75, NH, B), block 256 (4 waves). Each wave: 2 rows/pass,
// 5 passes. Cross (TOPK_MODE=false): bf16 K+V in LDS + fp32 transpose-reduce
// scratch (total 64,512 B). AWG (true): fp32 K in LDS (48,064 B), V gathered
// from global for the 16 winners.
// qp is pre-scaled by 1/sqrt(dk).
// ---------------------------------------------------------------------------
template <bool TOPK_MODE>
__global__ __launch_bounds__(256) void attn_kernel(
    const float* __restrict__ qp, const float* __restrict__ kp,
    const float* __restrict__ vp, float* __restrict__ ao)
{
  extern __shared__ char smem[];
  bf16*  KTb = (bf16*)smem;
  bf16*  VTb = KTb + 16 * PITCH_C;
  float* KTf = (float*)smem;
  float* red = (float*)(smem + 2 * 16 * PITCH_C * 2);  // offset 48,128 B

  const int t = threadIdx.x;
  const int h = blockIdx.y, b = blockIdx.z;
  const int qbase = blockIdx.x * TQ;
  const float* kslab = kp + (size_t)(b * LK) * 64 + h * 16;
  const float* vslab = vp + (size_t)(b * LK) * 64 + h * 16;

  for (int i = t; i < LK * 16; i += 256) {
    const int k = i >> 4, d = i & 15;
    const float kvv = kslab[(size_t)k * 64 + d];
    if constexpr (TOPK_MODE) {
      KTf[d * PITCH_A + k] = kvv;
    } else {
      KTb[d * PITCH_C + k] = __float2bfloat16(kvv);
      VTb[d * PITCH_C + k] = __float2bfloat16(vslab[(size_t)k * 64 + d]);
    }
  }
  __syncthreads();

  const int wave = t >> 6, lane = t & 63;

  for (int p = 0; p < TQ / 8; ++p) {
    const int r0 = qbase + wave * 2 + p * 8;
    const float* qrow = qp + ((size_t)(b * LQ + r0)) * 64 + h * 16;
    float q0[16], q1[16];
    #pragma unroll
    for (int d = 0; d < 16; ++d) { q0[d] = qrow[d]; q1[d] = qrow[64 + d]; }

    // logits for keys lane + 64*tt
    float lg0[12], lg1[12];
    #pragma unroll
    for (int tt = 0; tt < 12; ++tt) {
      const int k = lane + (tt << 6);
      if (tt < 11 || k < LK) {
        float a0 = 0.f, a1 = 0.f;
        #pragma unroll
        for (int d = 0; d < 16; ++d) {
          float kvv;
          if constexpr (TOPK_MODE) kvv = KTf[d * PITCH_A + k];
          else                     kvv = __bfloat162float(KTb[d * PITCH_C + k]);
          a0 = fmaf(kvv, q0[d], a0);
          a1 = fmaf(kvv, q1[d], a1);
        }
        lg0[tt] = a0; lg1[tt] = a1;
      } else {
        lg0[tt] = -1e30f; lg1[tt] = -1e30f;
      }
    }

    if constexpr (!TOPK_MODE) {
      // ---- full softmax ----
      float m0 = lg0[0], m1 = lg1[0];
      #pragma unroll
      for (int tt = 1; tt < 12; ++tt) { m0 = fmaxf(m0, lg0[tt]); m1 = fmaxf(m1, lg1[tt]); }
      #pragma unroll
      for (int off = 32; off > 0; off >>= 1) {
        m0 = fmaxf(m0, __shfl_xor(m0, off));
        m1 = fmaxf(m1, __shfl_xor(m1, off));
      }
      float s0 = 0.f, s1 = 0.f;
      #pragma unroll
      for (int tt = 0; tt < 12; ++tt) {
        lg0[tt] = __expf(lg0[tt] - m0); s0 += lg0[tt];
        lg1[tt] = __expf(lg1[tt] - m1); s1 += lg1[tt];
      }
      #pragma unroll
      for (int off = 32; off > 0; off >>= 1) {
        s0 += __shfl_xor(s0, off);
        s1 += __shfl_xor(s1, off);
      }
      // weighted V accumulation (per-lane partials over its 12 keys)
      float o0[16], o1[16];
      #pragma unroll
      for (int d = 0; d < 16; ++d) { o0[d] = 0.f; o1[d] = 0.f; }
      #pragma unroll
      for (int tt = 0; tt < 12; ++tt) {
        const int k = lane + (tt << 6);
        if (tt < 11 || k < LK) {
          const float w0 = lg0[tt], w1 = lg1[tt];
          #pragma unroll
          for (int d = 0; d < 16; ++d) {
            const float vv = __bfloat162float(VTb[d * PITCH_C + k]);
            o0[d] = fmaf(w0, vv, o0[d]);
            o1[d] = fmaf(w1, vv, o1[d]);
          }
        }
      }
      // transpose-reduce across the wave via swizzled LDS scratch, one row at a time
      const int dd = lane >> 2, g = lane & 3;
      float a0, a1;
      {
        #pragma unroll
        for (int d = 0; d < 16; ++d) red[t * 16 + ((d + t) & 15)] = o0[d];
        __syncthreads();
        float a = 0.f;
        #pragma unroll
        for (int i = 0; i < 16; ++i) {
          const int l2 = wave * 64 + g * 16 + i;
          a += red[l2 * 16 + ((dd + l2) & 15)];
        }
        __syncthreads();
        a += __shfl_xor(a, 1);
        a += __shfl_xor(a, 2);
        a0 = a;
      }
      {
        #pragma unroll
        for (int d = 0; d < 16; ++d) red[t * 16 + ((d + t) & 15)] = o1[d];
        __syncthreads();
        float a = 0.f;
        #pragma unroll
        for (int i = 0; i < 16; ++i) {
          const int l2 = wave * 64 + g * 16 + i;
          a += red[l2 * 16 + ((dd + l2) & 15)];
        }
        __syncthreads();
        a += __shfl_xor(a, 1);
        a += __shfl_xor(a, 2);
        a1 = a;
      }
      if (g == 0) {
        float* aor = ao + ((size_t)(b * LQ + r0)) * 64 + h * 16;
        aor[dd]      = a0 / s0;
        aor[64 + dd] = a1 / s1;
      }
    } else {
      // ---- AWG: exact top-16 + renormalize (full-softmax denominator cancels) ----
      float tv0[TK], tv1[TK];
      int   tk0[TK], tk1[TK];
      extract16(lg0, lane, tv0, tk0);
      extract16(lg1, lane, tv1, tk1);

      float e0[TK], e1[TK];
      float s0 = 0.f, s1 = 0.f;
      const float mm0 = tv0[0], mm1 = tv1[0];  // first extracted == max
      #pragma unroll
      for (int j = 0; j < TK; ++j) {
        e0[j] = __expf(tv0[j] - mm0); s0 += e0[j];
        e1[j] = __expf(tv1[j] - mm1); s1 += e1[j];
      }
      const float inv0 = 1.f / s0, inv1 = 1.f / s1;
      const int dd = lane & 15;
      const int rsel = (lane >> 4) & 1;
      const float* vbase = vp + (size_t)(b * LK) * 64 + h * 16;
      float acc = 0.f;
      #pragma unroll
      for (int j = 0; j < TK; ++j) {
        const float w = rsel ? e1[j] * inv1 : e0[j] * inv0;
        const int   k = rsel ? tk1[j] : tk0[j];
        acc = fmaf(w, vbase[(size_t)k * 64 + dd], acc);
      }
      if (lane < 32) {
        float* aor = ao + ((size_t)(b * LQ + r0 + rsel)) * 64 + h * 16;
        aor[dd] = acc;
      }
    }
  }
}

// ---------------------------------------------------------------------------
// x = LN(ao @ Wo + q_residual)     grid 3000, block 256
// ---------------------------------------------------------------------------
__global__ __launch_bounds__(256) void cross_out_kernel(
    const float* __restrict__ ao, const float* __restrict__ qres,
    const float* __restrict__ Wo, const float* __restrict__ g_,
    const float* __restrict__ b_, float* __restrict__ xout)
{
  __shared__ float Wl[64 * 65];
  __shared__ float xs[4][64];
  const int t = threadIdx.x, rr = t >> 6, cc = t & 63;
  const size_t row = (size_t)blockIdx.x * 4 + rr;
  for (int i = t; i < 4096; i += 256) Wl[(i >> 6) * 65 + (i & 63)] = Wo[i];
  xs[rr][cc] = ao[row * 64 + cc];
  __syncthreads();
  float acc = 0.f;
  #pragma unroll
  for (int c = 0; c < 64; ++c) acc = fmaf(xs[rr][c], Wl[c * 65 + cc], acc);
  acc += qres[row * 64 + cc];
  xout[row * 64 + cc] = row_ln(acc, g_[cc], b_[cc]);
}

// ---------------------------------------------------------------------------
// awg = LN(ao @ Wo + sg); x = qn + sg * sigmoid(awg)    grid 3000, block 256
// ---------------------------------------------------------------------------
__global__ __launch_bounds__(256) void awg_out_kernel(
    const float* __restrict__ ao, const float* __restrict__ sg,
    const float* __restrict__ qn, const float* __restrict__ Wo,
    const float* __restrict__ g_, const float* __restrict__ b_,
    float* __restrict__ xout)
{
  __shared__ float Wl[64 * 65];
  __shared__ float xs[4][64];
  const int t = threadIdx.x, rr = t >> 6, cc = t & 63;
  const size_t row = (size_t)blockIdx.x * 4 + rr;
  for (int i = t; i < 4096; i += 256) Wl[(i >> 6) * 65 + (i & 63)] = Wo[i];
  xs[rr][cc] = ao[row * 64 + cc];
  __syncthreads();
  float acc = 0.f;
  #pragma unroll
  for (int c = 0; c < 64; ++c) acc = fmaf(xs[rr][c], Wl[c * 65 + cc], acc);
  const float sgv = sg[row * 64 + cc];
  acc += sgv;
  const float awg = row_ln(acc, g_[cc], b_[cc]);
  xout[row * 64 + cc] = qn[row * 64 + cc] + sgv * sigmoidf(awg);
}

// ---------------------------------------------------------------------------
// qn = LN(x); sg = sigmoid(qn@W1+b1) * (qn@W2+b2)      grid 3000, block 256
// ---------------------------------------------------------------------------
__global__ __launch_bounds__(256) void qn_sg_kernel(
    const float* __restrict__ x, const float* __restrict__ lng,
    const float* __restrict__ lnb, const float* __restrict__ W1,
    const float* __restrict__ bb1, const float* __restrict__ W2,
    const float* __restrict__ bb2, float* __restrict__ qn,
    float* __restrict__ sg)
{
  __shared__ float qs[4][64];
  const int t = threadIdx.x, rr = t >> 6, cc = t & 63;
  const size_t row = (size_t)blockIdx.x * 4 + rr;
  const float v = x[row * 64 + cc];
  const float q = row_ln(v, lng[cc], lnb[cc]);
  qn[row * 64 + cc] = q;
  qs[rr][cc] = q;
  __syncthreads();
  float d1 = 0.f, d2 = 0.f;
  #pragma unroll 4
  for (int c = 0; c < 64; ++c) {
    const float xv = qs[rr][c];
    d1 = fmaf(xv, W1[c * 64 + cc], d1);
    d2 = fmaf(xv, W2[c * 64 + cc], d2);
  }
  d1 += bb1[cc];
  d2 += bb2[cc];
  sg[row * 64 + cc] = sigmoidf(d1) * d2;
}

// ---------------------------------------------------------------------------
// h = relu(x @ W1 + b1)  [64 -> 256]    grid 1500, block 256 (8 rows/block)
// ---------------------------------------------------------------------------
__global__ __launch_bounds__(256) void ffn1_kernel(
    const float* __restrict__ x, const float* __restrict__ W1,
    const float* __restrict__ b1, float* __restrict__ h)
{
  __shared__ float xs[8][64];
  const int t = threadIdx.x;
  const size_t r0 = (size_t)blockIdx.x * 8;
  for (int i = t; i < 512; i += 256) xs[i >> 6][i & 63] = x[r0 * 64 + i];
  __syncthreads();
  float acc[8];
  #pragma unroll
  for (int r = 0; r < 8; ++r) acc[r] = 0.f;
  for (int c = 0; c < 64; ++c) {
    const float w = W1[c * 256 + t];
    #pragma unroll
    for (int r = 0; r < 8; ++r) acc[r] = fmaf(xs[r][c], w, acc[r]);
  }
  const float bb = b1[t];
  #pragma unroll
  for (int r = 0; r < 8; ++r)
    h[(r0 + r) * 256 + t] = fmaxf(acc[r] + bb, 0.f);
}

// ---------------------------------------------------------------------------
// x = LN(h @ W2 + b2 + x)  [256 -> 64]   grid 3000, block 256 (in-place safe)
// ---------------------------------------------------------------------------
__global__ __launch_bounds__(256) void ffn2_kernel(
    const float* __restrict__ h, const float* __restrict__ xin,
    const float* __restrict__ W2, const float* __restrict__ b2,
    const float* __restrict__ g_, const float* __restrict__ b_,
    float* __restrict__ xout)
{
  __shared__ float hs[4][256];
  const int t = threadIdx.x, rr = t >> 6, cc = t & 63;
  const size_t row = (size_t)blockIdx.x * 4 + rr;
  for (int i = t; i < 1024; i += 256) hs[i >> 8][i & 255] = h[(size_t)blockIdx.x * 1024 + i];
  __syncthreads();
  float acc = 0.f;
  #pragma unroll 4
  for (int c = 0; c < 256; ++c) acc = fmaf(hs[rr][c], W2[c * 64 + cc], acc);
  acc += b2[cc];
  acc += xin[row * 64 + cc];
  xout[row * 64 + cc] = row_ln(acc, g_[cc], b_[cc]);
}

// ---------------------------------------------------------------------------
// out = sigmoid(x @ fcW + fcb)   grid 3000, block 256 (1 wave per row)
// OUTPUT IS FP32 (reference output dtype is float32).
// ---------------------------------------------------------------------------
__global__ __launch_bounds__(256) void final_kernel(
    const float* __restrict__ x, const float* __restrict__ fw,
    const float* __restrict__ fb, float* __restrict__ out)
{
  const int t = threadIdx.x, rr = t >> 6, cc = t & 63;
  const size_t row = (size_t)blockIdx.x * 4 + rr;
  float v = x[row * 64 + cc] * fw[cc];
  #pragma unroll
  for (int off = 32; off > 0; off >>= 1) v += __shfl_xor(v, off);
  if (cc == 0) out[row] = sigmoidf(v + fb[0]);
}

// ---------------------------------------------------------------------------
extern "C" void kernel_launch(void* const* d_in, const int* in_sizes, int n_in,
                              void* d_out, int out_size, void* d_ws, size_t ws_size,
                              hipStream_t stream) {
  (void)in_sizes; (void)n_in; (void)out_size; (void)ws_size;

  const float* q     = (const float*)d_in[0];
  const float* enc   = (const float*)d_in[1];
  const float* calWq = (const float*)d_in[2];
  const float* calWk = (const float*)d_in[3];
  const float* calWv = (const float*)d_in[4];
  const float* calWo = (const float*)d_in[5];
  const float* ln1g  = (const float*)d_in[6];
  const float* ln1b  = (const float*)d_in[7];
  const float* W1    = (const float*)d_in[8];
  const float* b1v   = (const float*)d_in[9];
  const float* W2    = (const float*)d_in[10];
  const float* b2v   = (const float*)d_in[11];
  const float* ln2g  = (const float*)d_in[12];
  const float* ln2b  = (const float*)d_in[13];
  const float* mlng  = (const float*)d_in[14];
  const float* mlnb  = (const float*)d_in[15];
  const float* mfc1W = (const float*)d_in[16];
  const float* mfc1b = (const float*)d_in[17];
  const float* mfc2W = (const float*)d_in[18];
  const float* mfc2b = (const float*)d_in[19];
  const float* mWq   = (const float*)d_in[20];
  const float* mWk   = (const float*)d_in[21];
  const float* mWv   = (const float*)d_in[22];
  const float* mWo   = (const float*)d_in[23];
  const float* malng = (const float*)d_in[24];
  const float* malnb = (const float*)d_in[25];
  const float* fcW   = (const float*)d_in[26];
  const float* fcb   = (const float*)d_in[27];
  float* out = (float*)d_out;

  float* ws  = (float*)d_ws;
  float* kv  = ws + WS_KV;
  float* xb  = ws + WS_XB;
  float* qp  = ws + WS_QP;
  float* aob = ws + WS_AO;
  float* qnb = ws + WS_QN;
  float* sgb = ws + WS_SG;
  float* hb  = ws + WS_HB;

  const float qscale = 0.25f;  // 1/sqrt(dk), dk=16
  const size_t crossLds = 2 * 16 * PITCH_C * sizeof(bf16) + 256 * 16 * sizeof(float); // 64,512
  const size_t awgLds   = 16 * PITCH_A * sizeof(float);                                // 48,064

  // 1) K/V projections for all three attention blocks
  kv_proj_kernel<<<dim3(750, 6), 256, 0, stream>>>(enc, calWk, calWv, mWk, mWv, kv);

  // 2) cross attention block
  proj_kernel<<<3000, 256, 0, stream>>>(q, calWq, qp, qscale);
  attn_kernel<false><<<dim3(75, NH_, B_), 256, crossLds, stream>>>(qp, kv, kv + 192000, aob);
  cross_out_kernel<<<3000, 256, 0, stream>>>(aob, q, calWo, ln1g, ln1b, xb);

  // 3) FFN
  ffn1_kernel<<<1500, 256, 0, stream>>>(xb, W1, b1v, hb);
  ffn2_kernel<<<3000, 256, 0, stream>>>(hb, xb, W2, b2v, ln2g, ln2b, xb);

  // 4) MGAN decoder layers
  for (int i = 0; i < 2; ++i) {
    qn_sg_kernel<<<3000, 256, 0, stream>>>(xb, mlng + i * 64, mlnb + i * 64,
                                           mfc1W + i * 4096, mfc1b + i * 64,
                                           mfc2W + i * 4096, mfc2b + i * 64,
                                           qnb, sgb);
    proj_kernel<<<3000, 256, 0, stream>>>(sgb, mWq + i * 4096, qp, qscale);
    attn_kernel<true><<<dim3(75, NH_, B_), 256, awgLds, stream>>>(
        qp, kv + (size_t)(2 + 2 * i) * 192000, kv + (size_t)(3 + 2 * i) * 192000, aob);
    awg_out_kernel<<<3000, 256, 0, stream>>>(aob, sgb, qnb, mWo + i * 4096,
                                             malng + i * 64, malnb + i * 64, xb);
  }

  // 5) head
  final_kernel<<<3000, 256, 0, stream>>>(xb, fcW, fcb, out);
}

// Round 5
// 653.607 us; speedup vs baseline: 2.4610x; 2.4610x over previous
//
#include <hip/hip_runtime.h>
#include <hip/hip_bf16.h>

using bf16 = __hip_bfloat16;

#define DEV_INLINE __device__ __forceinline__

// Problem constants
constexpr int B_  = 4;
constexpr int LQ  = 3000;
constexpr int LK  = 750;
constexpr int NH_ = 4;
constexpr float EPSF = 1e-6f;

// Attention LDS pitch (float2 / uint32 pair elements per d2-row), odd for bank spread
constexpr int PITCH = 753;

// Workspace layout (fp32 elements). Total 4,992,000 floats = ~20 MB.
constexpr size_t WS_KV = 0;        // 6 x B*LK*64 = 1,152,000
constexpr size_t WS_XB = 1152000;  // B*LQ*64 = 768,000
constexpr size_t WS_QP = 1920000;  // 768,000
constexpr size_t WS_AO = 2688000;  // 768,000
constexpr size_t WS_QN = 3456000;  // 768,000
constexpr size_t WS_SG = 4224000;  // 768,000
constexpr size_t WS_HB = 1920000;  // aliases QP..SG (dead during FFN): B*LQ*256

DEV_INLINE float sigmoidf(float x) { return 1.f / (1.f + __expf(-x)); }

// float -> bf16 bits (RNE), layout-agnostic
DEV_INLINE unsigned short f2bf(float f) {
  bf16 h = __float2bfloat16(f);
  unsigned short u;
  __builtin_memcpy(&u, &h, sizeof(u));
  return u;
}

// LayerNorm across one wave (64 threads == one row of 64 features).
DEV_INLINE float row_ln(float v, float g, float b) {
  float s1 = v, s2 = v * v;
  #pragma unroll
  for (int off = 32; off > 0; off >>= 1) {
    s1 += __shfl_xor(s1, off);
    s2 += __shfl_xor(s2, off);
  }
  const float m   = s1 * (1.f / 64.f);
  const float var = s2 * (1.f / 64.f) - m * m;
  return (v - m) * rsqrtf(var + EPSF) * g + b;
}

// ---------------------------------------------------------------------------
// K/V projections for enc with all 6 weight matrices. grid (750,6), block 256.
// ---------------------------------------------------------------------------
__global__ __launch_bounds__(256) void kv_proj_kernel(
    const float* __restrict__ enc,
    const float* __restrict__ calWk, const float* __restrict__ calWv,
    const float* __restrict__ mWk, const float* __restrict__ mWv,
    float* __restrict__ kv)
{
  __shared__ float Wl[64 * 65];
  __shared__ float xs[4][64];
  const int t = threadIdx.x;
  const float* W;
  switch (blockIdx.y) {
    case 0: W = calWk; break;
    case 1: W = calWv; break;
    case 2: W = mWk; break;
    case 3: W = mWv; break;
    case 4: W = mWk + 4096; break;
    default: W = mWv + 4096; break;
  }
  for (int i = t; i < 4096; i += 256) Wl[(i >> 6) * 65 + (i & 63)] = W[i];
  const int rr = t >> 6, cc = t & 63;
  const size_t row = (size_t)blockIdx.x * 4 + rr;
  xs[rr][cc] = enc[row * 64 + cc];
  __syncthreads();
  float acc = 0.f;
  #pragma unroll
  for (int c = 0; c < 64; ++c) acc = fmaf(xs[rr][c], Wl[c * 65 + cc], acc);
  kv[(size_t)blockIdx.y * (3000 * 64) + row * 64 + cc] = acc;
}

// ---------------------------------------------------------------------------
// Generic 64x64 projection: out = (x @ W) * scale.  grid 3000, block 256.
// ---------------------------------------------------------------------------
__global__ __launch_bounds__(256) void proj_kernel(
    const float* __restrict__ x, const float* __restrict__ W,
    float* __restrict__ out, float scale)
{
  __shared__ float Wl[64 * 65];
  __shared__ float xs[4][64];
  const int t = threadIdx.x, rr = t >> 6, cc = t & 63;
  const size_t row = (size_t)blockIdx.x * 4 + rr;
  for (int i = t; i < 4096; i += 256) Wl[(i >> 6) * 65 + (i & 63)] = W[i];
  xs[rr][cc] = x[row * 64 + cc];
  __syncthreads();
  float acc = 0.f;
  #pragma unroll
  for (int c = 0; c < 64; ++c) acc = fmaf(xs[rr][c], Wl[c * 65 + cc], acc);
  out[row * 64 + cc] = acc * scale;
}

// sortable uint: monotone with float order
DEV_INLINE unsigned int f2sort(float f) {
  int ib = __float_as_int(f);
  return (unsigned int)(ib ^ ((ib >> 31) | 0x80000000));
}

// ---------------------------------------------------------------------------
// CROSS attention. grid (375, NH, B), block 256 (4 waves, 1 row-pair/wave).
// K,V staged as bf16-pair words [8][PITCH]; per-wave barrier-free swizzled
// LDS transpose-reduce for PV. qp pre-scaled by 1/sqrt(dk).
// LDS: 2*8*PITCH*4 + 4*1024 = 52,288 B  -> 3 blocks/CU.
// ---------------------------------------------------------------------------
__global__ __launch_bounds__(256) void cross_attn_kernel(
    const float* __restrict__ qp, const float* __restrict__ kp,
    const float* __restrict__ vp, float* __restrict__ ao)
{
  extern __shared__ char smem[];
  unsigned int* KTw = (unsigned int*)smem;                  // [8][PITCH]
  unsigned int* VTw = KTw + 8 * PITCH;                      // [8][PITCH]
  float* red = (float*)(smem + 2 * 8 * PITCH * 4);          // [4 waves][256]

  const int t = threadIdx.x;
  const int h = blockIdx.y, b = blockIdx.z;
  const float* kslab = kp + (size_t)(b * LK) * 64 + h * 16;
  const float* vslab = vp + (size_t)(b * LK) * 64 + h * 16;

  // stage: each thread packs one key (16 dims) of K and V
  for (int k = t; k < LK; k += 256) {
    const float4* ks = (const float4*)(kslab + (size_t)k * 64);
    const float4* vs = (const float4*)(vslab + (size_t)k * 64);
    #pragma unroll
    for (int q4 = 0; q4 < 4; ++q4) {
      float4 a = ks[q4], v = vs[q4];
      KTw[(q4 * 2 + 0) * PITCH + k] = ((unsigned int)f2bf(a.y) << 16) | f2bf(a.x);
      KTw[(q4 * 2 + 1) * PITCH + k] = ((unsigned int)f2bf(a.w) << 16) | f2bf(a.z);
      VTw[(q4 * 2 + 0) * PITCH + k] = ((unsigned int)f2bf(v.y) << 16) | f2bf(v.x);
      VTw[(q4 * 2 + 1) * PITCH + k] = ((unsigned int)f2bf(v.w) << 16) | f2bf(v.z);
    }
  }
  __syncthreads();

  const int wave = t >> 6, lane = t & 63;
  const int r0 = blockIdx.x * 8 + wave * 2;
  const float* qrow = qp + ((size_t)(b * LQ + r0)) * 64 + h * 16;
  float q0[16], q1[16];
  #pragma unroll
  for (int d = 0; d < 16; ++d) { q0[d] = qrow[d]; q1[d] = qrow[64 + d]; }

  float lg0[12], lg1[12];
  #pragma unroll
  for (int tt = 0; tt < 12; ++tt) {
    const int k = lane + (tt << 6);
    if (tt < 11 || k < LK) {
      float a0 = 0.f, a1 = 0.f;
      #pragma unroll
      for (int d2 = 0; d2 < 8; ++d2) {
        const unsigned int w = KTw[d2 * PITCH + k];
        const float x = __int_as_float((int)(w << 16));
        const float y = __int_as_float((int)(w & 0xFFFF0000u));
        a0 = fmaf(x, q0[2 * d2], a0); a0 = fmaf(y, q0[2 * d2 + 1], a0);
        a1 = fmaf(x, q1[2 * d2], a1); a1 = fmaf(y, q1[2 * d2 + 1], a1);
      }
      lg0[tt] = a0; lg1[tt] = a1;
    } else {
      lg0[tt] = -1e30f; lg1[tt] = -1e30f;
    }
  }

  // softmax (full row)
  float m0 = lg0[0], m1 = lg1[0];
  #pragma unroll
  for (int tt = 1; tt < 12; ++tt) { m0 = fmaxf(m0, lg0[tt]); m1 = fmaxf(m1, lg1[tt]); }
  #pragma unroll
  for (int off = 32; off > 0; off >>= 1) {
    m0 = fmaxf(m0, __shfl_xor(m0, off));
    m1 = fmaxf(m1, __shfl_xor(m1, off));
  }
  float s0 = 0.f, s1 = 0.f;
  #pragma unroll
  for (int tt = 0; tt < 12; ++tt) {
    lg0[tt] = __expf(lg0[tt] - m0); s0 += lg0[tt];
    lg1[tt] = __expf(lg1[tt] - m1); s1 += lg1[tt];
  }
  #pragma unroll
  for (int off = 32; off > 0; off >>= 1) {
    s0 += __shfl_xor(s0, off);
    s1 += __shfl_xor(s1, off);
  }
  const float inv0 = 1.f / s0, inv1 = 1.f / s1;

  // PV in 4-dim chunks; per-wave barrier-free swizzled reduce
  float* red_w = red + wave * 256;
  const int dd = lane & 3, g = lane >> 2;
  float* aor0 = ao + ((size_t)(b * LQ + r0)) * 64 + h * 16;
  float* aor1 = aor0 + 64;

  #pragma unroll
  for (int c = 0; c < 4; ++c) {
    float o0[4] = {0.f, 0.f, 0.f, 0.f}, o1[4] = {0.f, 0.f, 0.f, 0.f};
    #pragma unroll
    for (int tt = 0; tt < 12; ++tt) {
      const int k = lane + (tt << 6);
      if (tt < 11 || k < LK) {
        const float w0 = lg0[tt], w1 = lg1[tt];
        #pragma unroll
        for (int dp = 0; dp < 2; ++dp) {
          const unsigned int w = VTw[(2 * c + dp) * PITCH + k];
          const float x = __int_as_float((int)(w << 16));
          const float y = __int_as_float((int)(w & 0xFFFF0000u));
          o0[2 * dp]     = fmaf(w0, x, o0[2 * dp]);
          o0[2 * dp + 1] = fmaf(w0, y, o0[2 * dp + 1]);
          o1[2 * dp]     = fmaf(w1, x, o1[2 * dp]);
          o1[2 * dp + 1] = fmaf(w1, y, o1[2 * dp + 1]);
        }
      }
    }
    // row 0 reduce (wave-private LDS, no barrier)
    #pragma unroll
    for (int d = 0; d < 4; ++d) red_w[d * 64 + ((lane + 16 * d) & 63)] = o0[d];
    float a = 0.f;
    #pragma unroll
    for (int j = 0; j < 4; ++j)
      a += red_w[dd * 64 + ((g + 16 * j + 16 * dd) & 63)];
    #pragma unroll
    for (int off = 4; off <= 32; off <<= 1) a += __shfl_xor(a, off);
    if (g == 0) aor0[c * 4 + dd] = a * inv0;
    // row 1 reduce (reuse region; in-wave lgkmcnt ordering)
    #pragma unroll
    for (int d = 0; d < 4; ++d) red_w[d * 64 + ((lane + 16 * d) & 63)] = o1[d];
    float a1r = 0.f;
    #pragma unroll
    for (int j = 0; j < 4; ++j)
      a1r += red_w[dd * 64 + ((g + 16 * j + 16 * dd) & 63)];
    #pragma unroll
    for (int off = 4; off <= 32; off <<= 1) a1r += __shfl_xor(a1r, off);
    if (g == 1) aor1[c * 4 + dd] = a1r * inv1;
  }
}

// ---------------------------------------------------------------------------
// AWG attention. grid (375, NH, B), block 256 (4 waves, 1 row-pair/wave).
// K in LDS float2 [8][PITCH]. Exact top-16 threshold via 32-round radix-greedy
// search with ballot counting; winners compacted (idx,val) to LDS; renormalized
// weights; V gathered from global. LDS: 48,192 + 1,536 = 49,728 B -> 3 blk/CU.
// ---------------------------------------------------------------------------
__global__ __launch_bounds__(256) void awg_attn_kernel(
    const float* __restrict__ qp, const float* __restrict__ kp,
    const float* __restrict__ vp, float* __restrict__ ao)
{
  extern __shared__ char smem[];
  float2* KT = (float2*)smem;                       // [8][PITCH]
  float*  cw = (float*)(smem + 8 * PITCH * 8);      // [4 waves][2 rows][24]
  int*    ci = (int*)(smem + 8 * PITCH * 8 + 768);  // [4 waves][2 rows][24]

  const int t = threadIdx.x;
  const int h = blockIdx.y, b = blockIdx.z;
  const float* kslab = kp + (size_t)(b * LK) * 64 + h * 16;

  for (int k = t; k < LK; k += 256) {
    const float4* ks = (const float4*)(kslab + (size_t)k * 64);
    #pragma unroll
    for (int q4 = 0; q4 < 4; ++q4) {
      float4 a = ks[q4];
      KT[(q4 * 2 + 0) * PITCH + k] = make_float2(a.x, a.y);
      KT[(q4 * 2 + 1) * PITCH + k] = make_float2(a.z, a.w);
    }
  }
  __syncthreads();

  const int wave = t >> 6, lane = t & 63;
  const int r0 = blockIdx.x * 8 + wave * 2;
  const float* qrow = qp + ((size_t)(b * LQ + r0)) * 64 + h * 16;
  float q0[16], q1[16];
  #pragma unroll
  for (int d = 0; d < 16; ++d) { q0[d] = qrow[d]; q1[d] = qrow[64 + d]; }

  float lg0[12], lg1[12];
  unsigned int u0[12], u1[12];
  #pragma unroll
  for (int tt = 0; tt < 12; ++tt) {
    const int k = lane + (tt << 6);
    if (tt < 11 || k < LK) {
      float a0 = 0.f, a1 = 0.f;
      #pragma unroll
      for (int d2 = 0; d2 < 8; ++d2) {
        const float2 kv = KT[d2 * PITCH + k];
        a0 = fmaf(kv.x, q0[2 * d2], a0); a0 = fmaf(kv.y, q0[2 * d2 + 1], a0);
        a1 = fmaf(kv.x, q1[2 * d2], a1); a1 = fmaf(kv.y, q1[2 * d2 + 1], a1);
      }
      lg0[tt] = a0; lg1[tt] = a1;
      u0[tt] = f2sort(a0); u1[tt] = f2sort(a1);
    } else {
      lg0[tt] = -1e30f; lg1[tt] = -1e30f;
      u0[tt] = 0u; u1[tt] = 0u;
    }
  }

  // 32-round greedy threshold search: T = max t with count(u >= t) >= 16
  unsigned int T0 = 0u, T1 = 0u;
  #pragma unroll
  for (int bit = 31; bit >= 0; --bit) {
    const unsigned int c0 = T0 | (1u << bit);
    const unsigned int c1 = T1 | (1u << bit);
    int n0 = 0, n1 = 0;
    #pragma unroll
    for (int tt = 0; tt < 12; ++tt) {
      n0 += __popcll(__ballot(u0[tt] >= c0));
      n1 += __popcll(__ballot(u1[tt] >= c1));
    }
    if (n0 >= 16) T0 = c0;
    if (n1 >= 16) T1 = c1;
  }

  // compact winners (idx, logit) into LDS via ballot prefix
  float* cw0 = cw + wave * 48;       float* cw1 = cw0 + 24;
  int*   ci0 = ci + wave * 48;       int*   ci1 = ci0 + 24;
  const unsigned long long below = (1ull << lane) - 1ull;
  int base0 = 0, base1 = 0;
  #pragma unroll
  for (int tt = 0; tt < 12; ++tt) {
    const int k = lane + (tt << 6);
    const bool p0 = (u0[tt] != 0u) && (u0[tt] >= T0);
    const bool p1 = (u1[tt] != 0u) && (u1[tt] >= T1);
    const unsigned long long m0 = __ballot(p0);
    const unsigned long long m1 = __ballot(p1);
    if (p0) {
      const int pos = base0 + __popcll(m0 & below);
      if (pos < 24) { cw0[pos] = lg0[tt]; ci0[pos] = k; }
    }
    if (p1) {
      const int pos = base1 + __popcll(m1 & below);
      if (pos < 24) { cw1[pos] = lg1[tt]; ci1[pos] = k; }
    }
    base0 += __popcll(m0);
    base1 += __popcll(m1);
  }
  const int cnt0 = min(base0, 24), cnt1 = min(base1, 24);

  // epilogue: lanes 0..31 row pair x dims; lanes 32..63 second half of keys
  const int dd = lane & 15;
  const int rsel = (lane >> 4) & 1;
  const int half = lane >> 5;
  const int cnt = rsel ? cnt1 : cnt0;
  const float* cwr = rsel ? cw1 : cw0;
  const int* cir = rsel ? ci1 : ci0;
  const float ref = cwr[0];
  const float* vbase = vp + (size_t)(b * LK) * 64 + h * 16 + dd;
  float acc = 0.f, Z = 0.f;
  for (int j = half; j < cnt; j += 2) {
    const float e = __expf(cwr[j] - ref);
    Z += e;
    acc = fmaf(e, vbase[(size_t)cir[j] * 64], acc);
  }
  acc += __shfl_xor(acc, 32);
  Z   += __shfl_xor(Z, 32);
  if (lane < 32)
    ao[((size_t)(b * LQ + r0 + rsel)) * 64 + h * 16 + dd] = acc / Z;
}

// ---------------------------------------------------------------------------
// x = LN(ao @ Wo + q_residual)     grid 3000, block 256
// ---------------------------------------------------------------------------
__global__ __launch_bounds__(256) void cross_out_kernel(
    const float* __restrict__ ao, const float* __restrict__ qres,
    const float* __restrict__ Wo, const float* __restrict__ g_,
    const float* __restrict__ b_, float* __restrict__ xout)
{
  __shared__ float Wl[64 * 65];
  __shared__ float xs[4][64];
  const int t = threadIdx.x, rr = t >> 6, cc = t & 63;
  const size_t row = (size_t)blockIdx.x * 4 + rr;
  for (int i = t; i < 4096; i += 256) Wl[(i >> 6) * 65 + (i & 63)] = Wo[i];
  xs[rr][cc] = ao[row * 64 + cc];
  __syncthreads();
  float acc = 0.f;
  #pragma unroll
  for (int c = 0; c < 64; ++c) acc = fmaf(xs[rr][c], Wl[c * 65 + cc], acc);
  acc += qres[row * 64 + cc];
  xout[row * 64 + cc] = row_ln(acc, g_[cc], b_[cc]);
}

// ---------------------------------------------------------------------------
// awg = LN(ao @ Wo + sg); x = qn + sg * sigmoid(awg)    grid 3000, block 256
// ---------------------------------------------------------------------------
__global__ __launch_bounds__(256) void awg_out_kernel(
    const float* __restrict__ ao, const float* __restrict__ sg,
    const float* __restrict__ qn, const float* __restrict__ Wo,
    const float* __restrict__ g_, const float* __restrict__ b_,
    float* __restrict__ xout)
{
  __shared__ float Wl[64 * 65];
  __shared__ float xs[4][64];
  const int t = threadIdx.x, rr = t >> 6, cc = t & 63;
  const size_t row = (size_t)blockIdx.x * 4 + rr;
  for (int i = t; i < 4096; i += 256) Wl[(i >> 6) * 65 + (i & 63)] = Wo[i];
  xs[rr][cc] = ao[row * 64 + cc];
  __syncthreads();
  float acc = 0.f;
  #pragma unroll
  for (int c = 0; c < 64; ++c) acc = fmaf(xs[rr][c], Wl[c * 65 + cc], acc);
  const float sgv = sg[row * 64 + cc];
  acc += sgv;
  const float awg = row_ln(acc, g_[cc], b_[cc]);
  xout[row * 64 + cc] = qn[row * 64 + cc] + sgv * sigmoidf(awg);
}

// ---------------------------------------------------------------------------
// qn = LN(x); sg = sigmoid(qn@W1+b1) * (qn@W2+b2)      grid 3000, block 256
// ---------------------------------------------------------------------------
__global__ __launch_bounds__(256) void qn_sg_kernel(
    const float* __restrict__ x, const float* __restrict__ lng,
    const float* __restrict__ lnb, const float* __restrict__ W1,
    const float* __restrict__ bb1, const float* __restrict__ W2,
    const float* __restrict__ bb2, float* __restrict__ qn,
    float* __restrict__ sg)
{
  __shared__ float qs[4][64];
  const int t = threadIdx.x, rr = t >> 6, cc = t & 63;
  const size_t row = (size_t)blockIdx.x * 4 + rr;
  const float v = x[row * 64 + cc];
  const float q = row_ln(v, lng[cc], lnb[cc]);
  qn[row * 64 + cc] = q;
  qs[rr][cc] = q;
  __syncthreads();
  float d1 = 0.f, d2 = 0.f;
  #pragma unroll 4
  for (int c = 0; c < 64; ++c) {
    const float xv = qs[rr][c];
    d1 = fmaf(xv, W1[c * 64 + cc], d1);
    d2 = fmaf(xv, W2[c * 64 + cc], d2);
  }
  d1 += bb1[cc];
  d2 += bb2[cc];
  sg[row * 64 + cc] = sigmoidf(d1) * d2;
}

// ---------------------------------------------------------------------------
// h = relu(x @ W1 + b1)  [64 -> 256]    grid 1500, block 256
// ---------------------------------------------------------------------------
__global__ __launch_bounds__(256) void ffn1_kernel(
    const float* __restrict__ x, const float* __restrict__ W1,
    const float* __restrict__ b1, float* __restrict__ h)
{
  __shared__ float xs[8][64];
  const int t = threadIdx.x;
  const size_t r0 = (size_t)blockIdx.x * 8;
  for (int i = t; i < 512; i += 256) xs[i >> 6][i & 63] = x[r0 * 64 + i];
  __syncthreads();
  float acc[8];
  #pragma unroll
  for (int r = 0; r < 8; ++r) acc[r] = 0.f;
  for (int c = 0; c < 64; ++c) {
    const float w = W1[c * 256 + t];
    #pragma unroll
    for (int r = 0; r < 8; ++r) acc[r] = fmaf(xs[r][c], w, acc[r]);
  }
  const float bb = b1[t];
  #pragma unroll
  for (int r = 0; r < 8; ++r)
    h[(r0 + r) * 256 + t] = fmaxf(acc[r] + bb, 0.f);
}

// ---------------------------------------------------------------------------
// x = LN(h @ W2 + b2 + x)  [256 -> 64]   grid 3000, block 256
// ---------------------------------------------------------------------------
__global__ __launch_bounds__(256) void ffn2_kernel(
    const float* __restrict__ h, const float* __restrict__ xin,
    const float* __restrict__ W2, const float* __restrict__ b2,
    const float* __restrict__ g_, const float* __restrict__ b_,
    float* __restrict__ xout)
{
  __shared__ float hs[4][256];
  const int t = threadIdx.x, rr = t >> 6, cc = t & 63;
  const size_t row = (size_t)blockIdx.x * 4 + rr;
  for (int i = t; i < 1024; i += 256) hs[i >> 8][i & 255] = h[(size_t)blockIdx.x * 1024 + i];
  __syncthreads();
  float acc = 0.f;
  #pragma unroll 4
  for (int c = 0; c < 256; ++c) acc = fmaf(hs[rr][c], W2[c * 64 + cc], acc);
  acc += b2[cc];
  acc += xin[row * 64 + cc];
  xout[row * 64 + cc] = row_ln(acc, g_[cc], b_[cc]);
}

// ---------------------------------------------------------------------------
// out = sigmoid(x @ fcW + fcb)   grid 3000, block 256. Output fp32.
// ---------------------------------------------------------------------------
__global__ __launch_bounds__(256) void final_kernel(
    const float* __restrict__ x, const float* __restrict__ fw,
    const float* __restrict__ fb, float* __restrict__ out)
{
  const int t = threadIdx.x, rr = t >> 6, cc = t & 63;
  const size_t row = (size_t)blockIdx.x * 4 + rr;
  float v = x[row * 64 + cc] * fw[cc];
  #pragma unroll
  for (int off = 32; off > 0; off >>= 1) v += __shfl_xor(v, off);
  if (cc == 0) out[row] = sigmoidf(v + fb[0]);
}

// ---------------------------------------------------------------------------
extern "C" void kernel_launch(void* const* d_in, const int* in_sizes, int n_in,
                              void* d_out, int out_size, void* d_ws, size_t ws_size,
                              hipStream_t stream) {
  (void)in_sizes; (void)n_in; (void)out_size; (void)ws_size;

  const float* q     = (const float*)d_in[0];
  const float* enc   = (const float*)d_in[1];
  const float* calWq = (const float*)d_in[2];
  const float* calWk = (const float*)d_in[3];
  const float* calWv = (const float*)d_in[4];
  const float* calWo = (const float*)d_in[5];
  const float* ln1g  = (const float*)d_in[6];
  const float* ln1b  = (const float*)d_in[7];
  const float* W1    = (const float*)d_in[8];
  const float* b1v   = (const float*)d_in[9];
  const float* W2    = (const float*)d_in[10];
  const float* b2v   = (const float*)d_in[11];
  const float* ln2g  = (const float*)d_in[12];
  const float* ln2b  = (const float*)d_in[13];
  const float* mlng  = (const float*)d_in[14];
  const float* mlnb  = (const float*)d_in[15];
  const float* mfc1W = (const float*)d_in[16];
  const float* mfc1b = (const float*)d_in[17];
  const float* mfc2W = (const float*)d_in[18];
  const float* mfc2b = (const float*)d_in[19];
  const float* mWq   = (const float*)d_in[20];
  const float* mWk   = (const float*)d_in[21];
  const float* mWv   = (const float*)d_in[22];
  const float* mWo   = (const float*)d_in[23];
  const float* malng = (const float*)d_in[24];
  const float* malnb = (const float*)d_in[25];
  const float* fcW   = (const float*)d_in[26];
  const float* fcb   = (const float*)d_in[27];
  float* out = (float*)d_out;

  float* ws  = (float*)d_ws;
  float* kv  = ws + WS_KV;
  float* xb  = ws + WS_XB;
  float* qp  = ws + WS_QP;
  float* aob = ws + WS_AO;
  float* qnb = ws + WS_QN;
  float* sgb = ws + WS_SG;
  float* hb  = ws + WS_HB;

  const float qscale = 0.25f;  // 1/sqrt(dk), dk=16
  const size_t crossLds = 2 * 8 * PITCH * 4 + 4 * 1024;        // 52,288 B
  const size_t awgLds   = 8 * PITCH * 8 + 768 + 768;           // 49,728 B

  // 1) K/V projections for all three attention blocks
  kv_proj_kernel<<<dim3(750, 6), 256, 0, stream>>>(enc, calWk, calWv, mWk, mWv, kv);

  // 2) cross attention block
  proj_kernel<<<3000, 256, 0, stream>>>(q, calWq, qp, qscale);
  cross_attn_kernel<<<dim3(375, NH_, B_), 256, crossLds, stream>>>(qp, kv, kv + 192000, aob);
  cross_out_kernel<<<3000, 256, 0, stream>>>(aob, q, calWo, ln1g, ln1b, xb);

  // 3) FFN
  ffn1_kernel<<<1500, 256, 0, stream>>>(xb, W1, b1v, hb);
  ffn2_kernel<<<3000, 256, 0, stream>>>(hb, xb, W2, b2v, ln2g, ln2b, xb);

  // 4) MGAN decoder layers
  for (int i = 0; i < 2; ++i) {
    qn_sg_kernel<<<3000, 256, 0, stream>>>(xb, mlng + i * 64, mlnb + i * 64,
                                           mfc1W + i * 4096, mfc1b + i * 64,
                                           mfc2W + i * 4096, mfc2b + i * 64,
                                           qnb, sgb);
    proj_kernel<<<3000, 256, 0, stream>>>(sgb, mWq + i * 4096, qp, qscale);
    awg_attn_kernel<<<dim3(375, NH_, B_), 256, awgLds, stream>>>(
        qp, kv + (size_t)(2 + 2 * i) * 192000, kv + (size_t)(3 + 2 * i) * 192000, aob);
    awg_out_kernel<<<3000, 256, 0, stream>>>(aob, sgb, qnb, mWo + i * 4096,
                                             malng + i * 64, malnb + i * 64, xb);
  }

  // 5) head
  final_kernel<<<3000, 256, 0, stream>>>(xb, fcW, fcb, out);
}